// Round 1
// baseline (78.996 us; speedup 1.0000x reference)
//
#include <hip/hip_runtime.h>
#include <math.h>

#define BB 16            // batch rows per block
#define NOUT 128
#define NIN 128
#define NTHREADS 256

__global__ __launch_bounds__(NTHREADS) void hyper_kernel(
    const float* __restrict__ x,
    const float* __restrict__ weight,
    const float* __restrict__ bias,
    float* __restrict__ out)
{
    __shared__ __align__(16) float sx[BB][NIN];
    __shared__ float svv[BB];

    const int tid = threadIdx.x;
    const int b0 = blockIdx.x * BB;

    // ---- stage x tile: BB*NIN = 2048 floats, 256 threads -> 2 float4 each
    {
        const float4* xg = (const float4*)(x + (size_t)b0 * NIN);
        float4* xs = (float4*)(&sx[0][0]);
        xs[tid] = xg[tid];
        xs[tid + NTHREADS] = xg[tid + NTHREADS];
    }
    __syncthreads();

    // ---- vv[r] = ||x[b0+r]||^2 : threads 0..127, 8 segs per row, shfl-reduce
    if (tid < 128) {
        const int r = tid >> 3, seg = tid & 7;
        float s = 0.f;
        const float4* xr = (const float4*)(&sx[r][seg * 16]);
        #pragma unroll
        for (int j = 0; j < 4; ++j) {
            float4 v = xr[j];
            s = fmaf(v.x, v.x, fmaf(v.y, v.y, fmaf(v.z, v.z, fmaf(v.w, v.w, s))));
        }
        s += __shfl_xor(s, 1);
        s += __shfl_xor(s, 2);
        s += __shfl_xor(s, 4);
        if (seg == 0) svv[r] = s;
    }

    // ---- main dot products: thread -> column o, rows rbase..rbase+7
    const int o = tid & 127;
    const int rbase = (tid >> 7) * (BB / 2);

    const float4* w4 = (const float4*)(weight + (size_t)o * NIN);
    const float4* b4 = (const float4*)(bias + (size_t)o * NIN);

    float accb[BB / 2], accw[BB / 2];
    #pragma unroll
    for (int r = 0; r < BB / 2; ++r) { accb[r] = 0.f; accw[r] = 0.f; }
    float uu = 0.f, bw = 0.f, ww = 0.f;

    #pragma unroll 4
    for (int kc = 0; kc < NIN / 4; ++kc) {
        const float4 wv = w4[kc];
        const float4 bv = b4[kc];
        // per-o stats (each thread reads its full rows anyway)
        uu = fmaf(bv.x, bv.x, uu); uu = fmaf(bv.y, bv.y, uu);
        uu = fmaf(bv.z, bv.z, uu); uu = fmaf(bv.w, bv.w, uu);
        bw = fmaf(bv.x, wv.x, bw); bw = fmaf(bv.y, wv.y, bw);
        bw = fmaf(bv.z, wv.z, bw); bw = fmaf(bv.w, wv.w, bw);
        ww = fmaf(wv.x, wv.x, ww); ww = fmaf(wv.y, wv.y, ww);
        ww = fmaf(wv.z, wv.z, ww); ww = fmaf(wv.w, wv.w, ww);
        #pragma unroll
        for (int r = 0; r < BB / 2; ++r) {
            const float4 xv = *(const float4*)(&sx[rbase + r][kc * 4]); // wave-uniform broadcast
            accb[r] = fmaf(xv.x, bv.x, accb[r]); accb[r] = fmaf(xv.y, bv.y, accb[r]);
            accb[r] = fmaf(xv.z, bv.z, accb[r]); accb[r] = fmaf(xv.w, bv.w, accb[r]);
            accw[r] = fmaf(xv.x, wv.x, accw[r]); accw[r] = fmaf(xv.y, wv.y, accw[r]);
            accw[r] = fmaf(xv.z, wv.z, accw[r]); accw[r] = fmaf(xv.w, wv.w, accw[r]);
        }
    }
    __syncthreads();   // svv ready for all

    // ---- epilogue
    const float EPS = 1.1920928955078125e-7f;     // float32 eps
    const float CLAMPV = 16.635532333438687f;     // log(2/eps)
    const float INV_SMOOTH = 1.f / 50.f;
    const float SMOOTHF = 50.f;
    const float MAXNORM = 1.f - 1e-5f;

    const float beta = 1.f - uu;                  // (1 - C*uu), unclipped
    const float beta_c = fmaxf(beta, EPS);        // a = beta_c * weight
    const float a_norm = fmaxf(beta_c * sqrtf(ww), 1e-15f);
    const float ba = beta_c * bw;                 // bias . a
    const float outcoef = (2.f / beta_c) * a_norm; // lam_b * a_norm
    const float inv_anorm = 1.f / a_norm;

    #pragma unroll
    for (int r = 0; r < BB / 2; ++r) {
        const float vv = svv[rbase + r];
        const float uv = -accb[r];                // sum u*v
        const float dax = beta_c * accw[r];       // x . a
        const float alpha = 1.f + 2.f * uv + vv;
        const float den = fmaxf(1.f + 2.f * uv + uu * vv, EPS);
        const float inv_den = 1.f / den;
        float suba = (beta * dax - alpha * ba) * inv_den;
        float ss = (alpha * alpha * uu + 2.f * alpha * beta * uv + beta * beta * vv)
                   * (inv_den * inv_den);
        // projection onto ball of radius (1-eps)
        const float nrm = fmaxf(sqrtf(fmaxf(ss, 0.f)), 1e-15f);
        if (nrm > MAXNORM) {
            const float sc = MAXNORM / nrm;
            suba *= sc;
            ss *= sc * sc;
        }
        const float lam_sub = 2.f / fmaxf(1.f - ss, EPS);
        const float arg = lam_sub * suba * inv_anorm;
        // smooth clamp: lo + (softplus(s*(x-lo)) - softplus(s*(x-hi)))/s, stable softplus
        const float t1 = SMOOTHF * (arg + CLAMPV);
        const float t2 = SMOOTHF * (arg - CLAMPV);
        const float sp1 = fmaxf(t1, 0.f) + log1pf(expf(-fabsf(t1)));
        const float sp2 = fmaxf(t2, 0.f) + log1pf(expf(-fabsf(t2)));
        const float scl = -CLAMPV + (sp1 - sp2) * INV_SMOOTH;
        const float sd = asinhf(scl);
        out[(size_t)(b0 + rbase + r) * NOUT + o] = outcoef * sd;
    }
}

extern "C" void kernel_launch(void* const* d_in, const int* in_sizes, int n_in,
                              void* d_out, int out_size, void* d_ws, size_t ws_size,
                              hipStream_t stream) {
    const float* x = (const float*)d_in[0];
    const float* w = (const float*)d_in[1];
    const float* b = (const float*)d_in[2];
    float* out = (float*)d_out;
    const int B = in_sizes[0] / NIN;       // 4096
    dim3 grid(B / BB), block(NTHREADS);
    hipLaunchKernelGGL(hyper_kernel, grid, block, 0, stream, x, w, b, out);
}